// Round 21
// baseline (495.279 us; speedup 1.0000x reference)
//
#include <hip/hip_runtime.h>
#include <hip/hip_bf16.h>
#include <hip/hip_fp16.h>

// ---------------------------------------------------------------------------
// GCN: 3x (GEMM -> sym-normalized aggregation(+self-loop) -> +bias -> ReLU)
//      -> global max pool per graph -> MLP head.
// GEMM via MFMA bf16 hi/lo split (3 products, ~16-bit mantissa):
//   512 thr (8 waves x 16 rows x BN cols). A direct global->register with
//   depth-2 raw prefetch surviving barriers: raw s_barrier + COUNTED
//   s_waitcnt vmcnt(N) (drains only W glds, keeps A loads in flight).
//   Uniform A-load counts via row clamping + pre-padded tail tile (xt).
//   W pre-converted into read-lane-ordered fragment planes, double-buffered
//   LDS via global_load_lds (conflict-free linear reads).
// All inter-layer tensors are single fp16 planes (lossless bf16 hi/lo split
//   in-register); agg gathers fp16, accumulates fp32.
// ---------------------------------------------------------------------------

typedef float f4u __attribute__((ext_vector_type(4), aligned(4)));
typedef unsigned short u16;
typedef u16 u16x8 __attribute__((ext_vector_type(8)));
typedef short bf16x8 __attribute__((ext_vector_type(8)));
typedef float f32x4 __attribute__((ext_vector_type(4)));
typedef _Float16 f16;
typedef f16 f16x8 __attribute__((ext_vector_type(8)));

__device__ __forceinline__ u16 bf16_rne(float f) {
    unsigned u = __float_as_uint(f);
    return (u16)((u + 0x7FFF + ((u >> 16) & 1)) >> 16);
}
__device__ __forceinline__ float bf16_f(u16 h) {
    return __uint_as_float(((unsigned)h) << 16);
}

__global__ void deg_count_kernel(const int* __restrict__ ei, int* __restrict__ cnt, int E) {
    int e = blockIdx.x * 256 + threadIdx.x;
    if (e < E) atomicAdd(&cnt[ei[E + e]], 1);
}

__global__ void deg_fin_kernel(const int* __restrict__ cnt, float* __restrict__ disq, int N) {
    int i = blockIdx.x * 256 + threadIdx.x;
    if (i < N) disq[i] = rsqrtf((float)cnt[i] + 1.0f);
}

__global__ void scan_pass1(const int* __restrict__ cnt, int* __restrict__ bsum, int N) {
    __shared__ int s[256];
    int t = threadIdx.x;
    int base = blockIdx.x * 1024 + t * 4;
    int sum = 0;
    #pragma unroll
    for (int j = 0; j < 4; ++j) { int idx = base + j; if (idx < N) sum += cnt[idx]; }
    s[t] = sum; __syncthreads();
    for (int off = 128; off; off >>= 1) {
        if (t < off) s[t] += s[t + off];
        __syncthreads();
    }
    if (t == 0) bsum[blockIdx.x] = s[0];
}

__global__ void scan_pass2(const int* __restrict__ bsum, int* __restrict__ boff,
                           int nchunks, int* __restrict__ rp, int N, int E) {
    __shared__ int s[256];
    int t = threadIdx.x;
    int v = (t < nchunks) ? bsum[t] : 0;
    s[t] = v; __syncthreads();
    for (int off = 1; off < 256; off <<= 1) {
        int x = (t >= off) ? s[t - off] : 0;
        __syncthreads();
        s[t] += x;
        __syncthreads();
    }
    boff[t] = s[t] - v;
    if (t == 0) rp[N] = E;
}

__global__ void scan_pass3(const int* __restrict__ cnt, const int* __restrict__ boff,
                           int* __restrict__ rp, int N) {
    __shared__ int s[256];
    int t = threadIdx.x;
    int base = blockIdx.x * 1024 + t * 4;
    int v[4]; int sum = 0;
    #pragma unroll
    for (int j = 0; j < 4; ++j) { int idx = base + j; v[j] = (idx < N) ? cnt[idx] : 0; sum += v[j]; }
    s[t] = sum; __syncthreads();
    for (int off = 1; off < 256; off <<= 1) {
        int x = (t >= off) ? s[t - off] : 0;
        __syncthreads();
        s[t] += x;
        __syncthreads();
    }
    int ex = s[t] - sum + boff[blockIdx.x];
    #pragma unroll
    for (int j = 0; j < 4; ++j) { int idx = base + j; if (idx < N) { rp[idx] = ex; ex += v[j]; } }
}

__global__ void scatter_kernel(const int* __restrict__ ei, const float* __restrict__ disq,
                               const int* __restrict__ rp, int* __restrict__ fill,
                               int2* __restrict__ esw, int E) {
    int e = blockIdx.x * 256 + threadIdx.x;
    if (e >= E) return;
    int s = ei[e];
    int d = ei[E + e];
    int pos = rp[d] + atomicAdd(&fill[d], 1);
    int2 p; p.x = s; p.y = __float_as_int(disq[s] * disq[d]);
    esw[pos] = p;
}

// ---- pad layer-1 tail tile: xt[i][j] = x[i][KP-32+j] (0 beyond K)
__global__ void pad_tail_kernel(const float* __restrict__ x, float* __restrict__ xt,
                                int N, int K, int KP) {
    int idx = blockIdx.x * 256 + threadIdx.x;
    if (idx >= N * 32) return;
    int i = idx >> 5, j = idx & 31;
    int k = KP - 32 + j;
    xt[idx] = (k < K) ? x[(long)i * K + k] : 0.f;
}

// ---- W convert into READ-LANE-ORDERED fragment hi/lo planes:
// Wf[((t*FC + fc)*64 + s)*8 + j] = conv(W[k][c]) with
//   c = fc*16 + (s&15), k = t*32 + ((s>>4)&3)*8 + j   (s = reading lane).
template <int BN>
__global__ void cvtw_kernel(const float* __restrict__ W, u16* __restrict__ Wfhi,
                            u16* __restrict__ Wflo, int K, int KP) {
    constexpr int FC = BN / 16;
    int idx = blockIdx.x * 256 + threadIdx.x;
    if (idx >= KP * BN) return;
    int j = idx & 7;
    int s = (idx >> 3) & 63;
    int tf = idx >> 9;            // t*FC + fc
    int fc = tf % FC;
    int t = tf / FC;
    int c = fc * 16 + (s & 15);
    int k = t * 32 + ((s >> 4) & 3) * 8 + j;
    float v = (k < K) ? W[(long)k * BN + c] : 0.f;
    u16 h = bf16_rne(v);
    Wfhi[idx] = h;
    Wflo[idx] = bf16_rne(v - bf16_f(h));
}

// ---- MFMA GEMM: Xh[N,BN] fp16 = A[N,K] @ W[K,BN] via bf16 hi/lo split.
// BM=128, BK=32, 512 thr (8 waves x 16 rows). Depth-2 A prefetch with
// counted-vmcnt barriers (A loads survive the barrier).
// AMODE: 0 = fp32 A (layer 1, tail tile from Xt), 1 = fp16-plane A.
template <int BN, int AMODE>
__global__ __launch_bounds__(512) void mfma_gemm(
    const float* __restrict__ Af, const float* __restrict__ Xt,
    const f16* __restrict__ Ah16,
    const u16* __restrict__ Wfhi, const u16* __restrict__ Wflo,
    f16* __restrict__ Xh, int N, int K, int KP)
{
    constexpr int FC = BN / 16;
    constexpr int PLANE = BN * 32;            // u16 per plane per k-tile
    __shared__ u16 Wlds[2][2 * PLANE];        // [buf][hi | lo]
    const int tid = threadIdx.x;
    const int w = tid >> 6;                   // wave 0..7
    const int l = tid & 63;
    const int l15 = l & 15;
    const int g = l >> 4;
    const int koff = g * 8;
    const long base = (long)blockIdx.x * 128;
    const long arow = base + w * 16 + l15;
    const bool rowOK = (arow < N);
    const long arow_c = rowOK ? arow : 0;     // clamped (uniform load counts)
    const float keepm = rowOK ? 1.f : 0.f;
    const int bro = l * 8;                    // linear per-lane frag offset (u16)
    const int T = KP / 32;

    f32x4 acc[FC];
    #pragma unroll
    for (int j = 0; j < FC; ++j) acc[j] = (f32x4){0.f, 0.f, 0.f, 0.f};

    auto stageW = [&](int t, int buf) {
        if (BN == 128 || tid < PLANE / 8) {
            const u16* gph = Wfhi + (long)t * PLANE + tid * 8;
            const u16* gpl = Wflo + (long)t * PLANE + tid * 8;
            __builtin_amdgcn_global_load_lds(
                (const __attribute__((address_space(1))) void*)gph,
                (__attribute__((address_space(3))) void*)((char*)&Wlds[buf][0] + w * 1024), 16, 0, 0);
            __builtin_amdgcn_global_load_lds(
                (const __attribute__((address_space(1))) void*)gpl,
                (__attribute__((address_space(3))) void*)((char*)&Wlds[buf][PLANE] + w * 1024), 16, 0, 0);
        }
        asm volatile("" ::: "memory");        // pin issue order: W glds oldest
    };
    // counted-vmcnt barrier: drain W glds, keep A prefetch in flight
    auto syncw = [&](bool keepA) {
        if (keepA) {
            if constexpr (AMODE == 0) asm volatile("s_waitcnt vmcnt(2)" ::: "memory");
            else                      asm volatile("s_waitcnt vmcnt(1)" ::: "memory");
        } else {
            asm volatile("s_waitcnt vmcnt(0)" ::: "memory");
        }
        __builtin_amdgcn_s_barrier();
        asm volatile("" ::: "memory");
    };
    // raw A loads -- fp32 path: always exactly 2 dwordx4 when t<T
    auto loadRawF = [&](int t, f4u& ra, f4u& rb) {
        if (t < T) {
            const float* ap = (t == T - 1) ? &Xt[arow_c * 32 + koff]
                                           : &Af[arow_c * (long)K + t * 32 + koff];
            ra = *(const f4u*)ap;
            rb = *(const f4u*)(ap + 4);
        } else {
            ra = (f4u){0.f, 0.f, 0.f, 0.f};
            rb = (f4u){0.f, 0.f, 0.f, 0.f};
        }
    };
    auto convF = [&](const f4u& ra, const f4u& rb, bf16x8& ah, bf16x8& al) {
        float f[8] = {ra.x, ra.y, ra.z, ra.w, rb.x, rb.y, rb.z, rb.w};
        u16x8 hv, lv;
        #pragma unroll
        for (int j = 0; j < 8; ++j) {
            float fv = f[j] * keepm;
            u16 h = bf16_rne(fv);
            hv[j] = h;
            lv[j] = bf16_rne(fv - bf16_f(h));
        }
        ah = __builtin_bit_cast(bf16x8, hv);
        al = __builtin_bit_cast(bf16x8, lv);
    };
    // raw A loads -- fp16-plane path: always exactly 1 x 16B when t<T
    auto loadRawH = [&](int t, u16x8& q) {
        if (t < T) q = *(const u16x8*)&Ah16[arow_c * (long)K + t * 32 + koff];
        else       q = (u16x8)0;
    };
    auto convH = [&](const u16x8& q, bf16x8& ah, bf16x8& al) {
        f16x8 v = __builtin_bit_cast(f16x8, q);
        u16x8 hv, lv;
        #pragma unroll
        for (int j = 0; j < 8; ++j) {
            float f = (float)v[j] * keepm;
            u16 h = bf16_rne(f);
            hv[j] = h;
            lv[j] = bf16_rne(f - bf16_f(h));
        }
        ah = __builtin_bit_cast(bf16x8, hv);
        al = __builtin_bit_cast(bf16x8, lv);
    };
    auto domfma = [&](const bf16x8& ah, const bf16x8& al, int buf) {
        #pragma unroll
        for (int fc = 0; fc < FC; ++fc) {
            bf16x8 bh = *(const bf16x8*)&Wlds[buf][fc * 512 + bro];
            bf16x8 bl = *(const bf16x8*)&Wlds[buf][PLANE + fc * 512 + bro];
            acc[fc] = __builtin_amdgcn_mfma_f32_16x16x32_bf16(ah, bh, acc[fc], 0, 0, 0);
            acc[fc] = __builtin_amdgcn_mfma_f32_16x16x32_bf16(al, bh, acc[fc], 0, 0, 0);
            acc[fc] = __builtin_amdgcn_mfma_f32_16x16x32_bf16(ah, bl, acc[fc], 0, 0, 0);
        }
    };

    // static slots (no dynamic indexing -> stay in registers)
    f4u r0a, r0b, r1a, r1b;
    u16x8 q0, q1;
    bf16x8 a0h, a0l, a1h, a1l;

    // prologue: W(0) staged; raw A(0), A(1) in flight; A(0) converted
    stageW(0, 0);
    if constexpr (AMODE == 0) {
        loadRawF(0, r0a, r0b);
        loadRawF(1, r1a, r1b);
        convF(r0a, r0b, a0h, a0l);      // waits A(0) -> drains W(0) too (FIFO)
    } else {
        loadRawH(0, q0);
        loadRawH(1, q1);
        convH(q0, a0h, a0l);
    }
    syncw(true);                        // keeps A(1) in flight

    for (int t = 0; t < T; t += 2) {
        // ---- even tile: reads buf0
        if (t + 1 < T) stageW(t + 1, 1);
        if constexpr (AMODE == 0) loadRawF(t + 2, r0a, r0b);
        else                      loadRawH(t + 2, q0);
        domfma(a0h, a0l, 0);
        if constexpr (AMODE == 0) convF(r1a, r1b, a1h, a1l);
        else                      convH(q1, a1h, a1l);
        syncw(t + 2 < T);
        // ---- odd tile: reads buf1
        if (t + 1 < T) {
            if (t + 2 < T) stageW(t + 2, 0);
            if constexpr (AMODE == 0) loadRawF(t + 3, r1a, r1b);
            else                      loadRawH(t + 3, q1);
            domfma(a1h, a1l, 1);
            if constexpr (AMODE == 0) convF(r0a, r0b, a0h, a0l);
            else                      convH(q0, a0h, a0l);
            syncw(t + 3 < T);
        }
    }
    // ---- epilogue: fp16 plane. D col=lane&15, row=(lane>>4)*4+reg
    #pragma unroll
    for (int fc = 0; fc < FC; ++fc) {
        int col = fc * 16 + l15;
        #pragma unroll
        for (int reg = 0; reg < 4; ++reg) {
            long row = base + w * 16 + g * 4 + reg;
            if (row < N) Xh[row * BN + col] = (f16)acc[fc][reg];
        }
    }
}

// ---- aggregation from fp16 plane -> fp16 plane:
// h[i] = relu( sum_e xh[src_e]*nv_e + xh[i]*disq[i]^2 + bias ), fp32 accum.
template <int C>
__global__ __launch_bounds__(256) void agg_kernel(
    const f16* __restrict__ xh, const float* __restrict__ disq,
    const int* __restrict__ rp, const int2* __restrict__ esw,
    const float* __restrict__ bias, f16* __restrict__ hout, int N)
{
    int i = blockIdx.x * 4 + (threadIdx.x >> 6);
    if (i >= N) return;
    int lane = threadIdx.x & 63;
    int e0 = rp[i], e1 = rp[i + 1];
    constexpr int LPE = C / 8;            // lanes per edge (16 or 8)
    constexpr int EPW = 64 / LPE;         // edges per wave load (4 or 8)
    int sub = lane / LPE;
    int col = lane % LPE;                 // 8-half group within row
    const f16x8* x8 = (const f16x8*)xh;

    float a0[8], a1[8];
    #pragma unroll
    for (int j = 0; j < 8; ++j) { a0[j] = 0.f; a1[j] = 0.f; }

    int e = e0 + sub;
    for (; e + EPW < e1; e += 2 * EPW) {
        int2 p0 = esw[e];
        int2 p1 = esw[e + EPW];
        f16x8 v0 = x8[(long)p0.x * LPE + col];
        f16x8 v1 = x8[(long)p1.x * LPE + col];
        float w0 = __int_as_float(p0.y), w1 = __int_as_float(p1.y);
        #pragma unroll
        for (int j = 0; j < 8; ++j) {
            a0[j] += (float)v0[j] * w0;
            a1[j] += (float)v1[j] * w1;
        }
    }
    for (; e < e1; e += EPW) {
        int2 p0 = esw[e];
        f16x8 v0 = x8[(long)p0.x * LPE + col];
        float w0 = __int_as_float(p0.y);
        #pragma unroll
        for (int j = 0; j < 8; ++j) a0[j] += (float)v0[j] * w0;
    }
    #pragma unroll
    for (int j = 0; j < 8; ++j) a0[j] += a1[j];
    #pragma unroll
    for (int m = LPE; m < 64; m <<= 1) {
        #pragma unroll
        for (int j = 0; j < 8; ++j) a0[j] += __shfl_xor(a0[j], m, 64);
    }
    if (sub == 0) {
        float ds = disq[i];
        float ws = ds * ds;
        f16x8 v = x8[(long)i * LPE + col];
        const float* bp = bias + col * 8;
        float4 b0 = *(const float4*)bp;
        float4 b1 = *(const float4*)(bp + 4);
        float bb[8] = {b0.x, b0.y, b0.z, b0.w, b1.x, b1.y, b1.z, b1.w};
        f16x8 o;
        #pragma unroll
        for (int j = 0; j < 8; ++j)
            o[j] = (f16)fmaxf(a0[j] + (float)v[j] * ws + bb[j], 0.f);
        *(f16x8*)&hout[(long)i * C + col * 8] = o;
    }
}

// ---- global max pool (fp16 in): batch sorted -> running max, flush on change
__global__ __launch_bounds__(256) void pool_kernel(
    const f16* __restrict__ h, const int* __restrict__ batch,
    float* __restrict__ g, int N)
{
    int c = threadIdx.x & 63;
    int slot = threadIdx.x >> 6;
    int base = blockIdx.x * 512;
    int end = base + 512; if (end > N) end = N;
    int cur = -1; float m = 0.f;
    for (int n = base + slot; n < end; n += 4) {
        int b = batch[n];
        float v = (float)h[(long)n * 64 + c];
        if (b != cur) {
            if (cur >= 0) atomicMax((int*)&g[cur * 64 + c], __float_as_int(m));
            cur = b; m = v;
        } else {
            m = fmaxf(m, v);
        }
    }
    if (cur >= 0) atomicMax((int*)&g[cur * 64 + c], __float_as_int(m));
}

// ---- head: out[r] = relu(g[r]@Wh1+bh1) @ Wh2 + bh2
__global__ void head_kernel(const float* __restrict__ g, const float* __restrict__ Wh1,
                            const float* __restrict__ bh1, const float* __restrict__ Wh2,
                            const float* __restrict__ bh2, float* __restrict__ out, int G) {
    int r = threadIdx.x;
    if (r >= G) return;
    float hid[32];
    #pragma unroll
    for (int j = 0; j < 32; ++j) {
        float s = bh1[j];
        for (int k = 0; k < 64; ++k) s += g[r * 64 + k] * Wh1[k * 32 + j];
        hid[j] = fmaxf(s, 0.f);
    }
    float o = bh2[0];
    #pragma unroll
    for (int j = 0; j < 32; ++j) o += hid[j] * Wh2[j];
    out[r] = o;
}

extern "C" void kernel_launch(void* const* d_in, const int* in_sizes, int n_in,
                              void* d_out, int out_size, void* d_ws, size_t ws_size,
                              hipStream_t stream) {
    const float* x   = (const float*)d_in[0];
    const int*   ei  = (const int*)d_in[1];
    const int*   bat = (const int*)d_in[2];
    const float* W1  = (const float*)d_in[3];
    const float* b1  = (const float*)d_in[4];
    const float* W2  = (const float*)d_in[5];
    const float* b2  = (const float*)d_in[6];
    const float* W3  = (const float*)d_in[7];
    const float* b3  = (const float*)d_in[8];
    const float* Wh1 = (const float*)d_in[9];
    const float* bh1 = (const float*)d_in[10];
    const float* Wh2 = (const float*)d_in[11];
    const float* bh2 = (const float*)d_in[12];
    float* out = (float*)d_out;

    const int N = in_sizes[2];
    const int E = in_sizes[1] / 2;
    const int K1 = in_sizes[0] / N;          // 397
    const int G = out_size;                  // 64
    const int KP1 = ((K1 + 31) / 32) * 32;   // 416

    char* wsp = (char*)d_ws;
    size_t off = 0;
    auto alloc = [&](size_t bytes) -> void* {
        void* p = wsp + off;
        off = (off + bytes + 255) & ~(size_t)255;
        return p;
    };
    int*   cnt   = (int*)alloc((size_t)N * 4);
    float* disq  = (float*)alloc((size_t)N * 4);
    int*   rp    = (int*)alloc((size_t)(N + 1) * 4);
    int*   bsum  = (int*)alloc(256 * 4);
    int*   boff  = (int*)alloc(256 * 4);
    int2*  esw   = (int2*)alloc((size_t)E * 8);
    u16*   Wf1hi = (u16*)alloc((size_t)KP1 * 128 * 2);
    u16*   Wf1lo = (u16*)alloc((size_t)KP1 * 128 * 2);
    u16*   Wf2hi = (u16*)alloc((size_t)128 * 128 * 2);
    u16*   Wf2lo = (u16*)alloc((size_t)128 * 128 * 2);
    u16*   Wf3hi = (u16*)alloc((size_t)128 * 64 * 2);
    u16*   Wf3lo = (u16*)alloc((size_t)128 * 64 * 2);
    float* xt    = (float*)alloc((size_t)N * 32 * 4);    // padded layer-1 tail
    f16*   Xh    = (f16*)alloc((size_t)N * 128 * 2);     // GEMM out plane
    f16*   Hh    = (f16*)alloc((size_t)N * 128 * 2);     // agg out plane
    float* g     = (float*)alloc((size_t)G * 64 * 4);

    const int nchunks = (N + 1023) / 1024;

    (void)hipMemsetAsync(cnt, 0, (size_t)N * 4, stream);
    deg_count_kernel<<<(E + 255) / 256, 256, 0, stream>>>(ei, cnt, E);
    deg_fin_kernel<<<(N + 255) / 256, 256, 0, stream>>>(cnt, disq, N);
    scan_pass1<<<nchunks, 256, 0, stream>>>(cnt, bsum, N);
    scan_pass2<<<1, 256, 0, stream>>>(bsum, boff, nchunks, rp, N, E);
    scan_pass3<<<nchunks, 256, 0, stream>>>(cnt, boff, rp, N);
    (void)hipMemsetAsync(cnt, 0, (size_t)N * 4, stream);
    scatter_kernel<<<(E + 255) / 256, 256, 0, stream>>>(ei, disq, rp, cnt, esw, E);

    // weight conversions (tiny, read-lane-ordered fragments) + tail pad
    cvtw_kernel<128><<<(KP1 * 128 + 255) / 256, 256, 0, stream>>>(W1, Wf1hi, Wf1lo, K1, KP1);
    cvtw_kernel<128><<<(128 * 128 + 255) / 256, 256, 0, stream>>>(W2, Wf2hi, Wf2lo, 128, 128);
    cvtw_kernel<64><<<(128 * 64 + 255) / 256, 256, 0, stream>>>(W3, Wf3hi, Wf3lo, 128, 128);
    pad_tail_kernel<<<((N * 32) + 255) / 256, 256, 0, stream>>>(x, xt, N, K1, KP1);

    int gblocks = (N + 127) / 128;
    int ablocks = (N + 3) / 4;
    // layer 1
    mfma_gemm<128, 0><<<gblocks, 512, 0, stream>>>(x, xt, nullptr, Wf1hi, Wf1lo, Xh, N, K1, KP1);
    agg_kernel<128><<<ablocks, 256, 0, stream>>>(Xh, disq, rp, esw, b1, Hh, N);
    // layer 2
    mfma_gemm<128, 1><<<gblocks, 512, 0, stream>>>(nullptr, nullptr, Hh, Wf2hi, Wf2lo, Xh, N, 128, 128);
    agg_kernel<128><<<ablocks, 256, 0, stream>>>(Xh, disq, rp, esw, b2, Hh, N);
    // layer 3
    mfma_gemm<64, 1><<<gblocks, 512, 0, stream>>>(nullptr, nullptr, Hh, Wf3hi, Wf3lo, Xh, N, 128, 128);
    agg_kernel<64><<<ablocks, 256, 0, stream>>>(Xh, disq, rp, esw, b3, Hh, N);
    // pool + head
    (void)hipMemsetAsync(g, 0, (size_t)G * 64 * 4, stream);
    pool_kernel<<<(N + 511) / 512, 256, 0, stream>>>(Hh, bat, g, N);
    head_kernel<<<1, 64, 0, stream>>>(g, Wh1, bh1, Wh2, bh2, out, G);
}

// Round 22
// 477.450 us; speedup vs baseline: 1.0373x; 1.0373x over previous
//
#include <hip/hip_runtime.h>
#include <hip/hip_bf16.h>
#include <hip/hip_fp16.h>

// ---------------------------------------------------------------------------
// GCN: 3x (GEMM -> sym-normalized aggregation(+self-loop) -> +bias -> ReLU)
//      -> global max pool per graph -> MLP head.
// GEMM via MFMA bf16 hi/lo split (3 products, ~16-bit mantissa):
//   512 thr (8 waves x 16 rows x BN cols). A direct global->register with
//   depth-2 raw prefetch; W pre-converted into read-lane-ordered fragment
//   planes, double-buffered LDS via global_load_lds (conflict-free reads).
// ALL inter-layer tensors are single fp16 planes (fp16 -> bf16 hi/lo split
//   is lossless in-register): agg writes fp16, GEMM reads fp16.
// ---------------------------------------------------------------------------

typedef float f4u __attribute__((ext_vector_type(4), aligned(4)));
typedef unsigned short u16;
typedef u16 u16x8 __attribute__((ext_vector_type(8)));
typedef short bf16x8 __attribute__((ext_vector_type(8)));
typedef float f32x4 __attribute__((ext_vector_type(4)));
typedef _Float16 f16;
typedef f16 f16x8 __attribute__((ext_vector_type(8)));

__device__ __forceinline__ u16 bf16_rne(float f) {
    unsigned u = __float_as_uint(f);
    return (u16)((u + 0x7FFF + ((u >> 16) & 1)) >> 16);
}
__device__ __forceinline__ float bf16_f(u16 h) {
    return __uint_as_float(((unsigned)h) << 16);
}

__global__ void deg_count_kernel(const int* __restrict__ ei, int* __restrict__ cnt, int E) {
    int e = blockIdx.x * 256 + threadIdx.x;
    if (e < E) atomicAdd(&cnt[ei[E + e]], 1);
}

__global__ void deg_fin_kernel(const int* __restrict__ cnt, float* __restrict__ disq, int N) {
    int i = blockIdx.x * 256 + threadIdx.x;
    if (i < N) disq[i] = rsqrtf((float)cnt[i] + 1.0f);
}

__global__ void scan_pass1(const int* __restrict__ cnt, int* __restrict__ bsum, int N) {
    __shared__ int s[256];
    int t = threadIdx.x;
    int base = blockIdx.x * 1024 + t * 4;
    int sum = 0;
    #pragma unroll
    for (int j = 0; j < 4; ++j) { int idx = base + j; if (idx < N) sum += cnt[idx]; }
    s[t] = sum; __syncthreads();
    for (int off = 128; off; off >>= 1) {
        if (t < off) s[t] += s[t + off];
        __syncthreads();
    }
    if (t == 0) bsum[blockIdx.x] = s[0];
}

__global__ void scan_pass2(const int* __restrict__ bsum, int* __restrict__ boff,
                           int nchunks, int* __restrict__ rp, int N, int E) {
    __shared__ int s[256];
    int t = threadIdx.x;
    int v = (t < nchunks) ? bsum[t] : 0;
    s[t] = v; __syncthreads();
    for (int off = 1; off < 256; off <<= 1) {
        int x = (t >= off) ? s[t - off] : 0;
        __syncthreads();
        s[t] += x;
        __syncthreads();
    }
    boff[t] = s[t] - v;
    if (t == 0) rp[N] = E;
}

__global__ void scan_pass3(const int* __restrict__ cnt, const int* __restrict__ boff,
                           int* __restrict__ rp, int N) {
    __shared__ int s[256];
    int t = threadIdx.x;
    int base = blockIdx.x * 1024 + t * 4;
    int v[4]; int sum = 0;
    #pragma unroll
    for (int j = 0; j < 4; ++j) { int idx = base + j; v[j] = (idx < N) ? cnt[idx] : 0; sum += v[j]; }
    s[t] = sum; __syncthreads();
    for (int off = 1; off < 256; off <<= 1) {
        int x = (t >= off) ? s[t - off] : 0;
        __syncthreads();
        s[t] += x;
        __syncthreads();
    }
    int ex = s[t] - sum + boff[blockIdx.x];
    #pragma unroll
    for (int j = 0; j < 4; ++j) { int idx = base + j; if (idx < N) { rp[idx] = ex; ex += v[j]; } }
}

__global__ void scatter_kernel(const int* __restrict__ ei, const float* __restrict__ disq,
                               const int* __restrict__ rp, int* __restrict__ fill,
                               int2* __restrict__ esw, int E) {
    int e = blockIdx.x * 256 + threadIdx.x;
    if (e >= E) return;
    int s = ei[e];
    int d = ei[E + e];
    int pos = rp[d] + atomicAdd(&fill[d], 1);
    int2 p; p.x = s; p.y = __float_as_int(disq[s] * disq[d]);
    esw[pos] = p;
}

// ---- W convert into READ-LANE-ORDERED fragment hi/lo planes:
// Wf[((t*FC + fc)*64 + s)*8 + j] = conv(W[k][c]) with
//   c = fc*16 + (s&15), k = t*32 + ((s>>4)&3)*8 + j   (s = reading lane).
template <int BN>
__global__ void cvtw_kernel(const float* __restrict__ W, u16* __restrict__ Wfhi,
                            u16* __restrict__ Wflo, int K, int KP) {
    constexpr int FC = BN / 16;
    int idx = blockIdx.x * 256 + threadIdx.x;
    if (idx >= KP * BN) return;
    int j = idx & 7;
    int s = (idx >> 3) & 63;
    int tf = idx >> 9;            // t*FC + fc
    int fc = tf % FC;
    int t = tf / FC;
    int c = fc * 16 + (s & 15);
    int k = t * 32 + ((s >> 4) & 3) * 8 + j;
    float v = (k < K) ? W[(long)k * BN + c] : 0.f;
    u16 h = bf16_rne(v);
    Wfhi[idx] = h;
    Wflo[idx] = bf16_rne(v - bf16_f(h));
}

// ---- MFMA GEMM: Xh[N,BN] fp16 = A[N,K] @ W[K,BN] via bf16 hi/lo split.
// BM=128, BK=32, 512 thr (8 waves x 16 rows). Depth-2 A prefetch.
// AMODE: 0 = fp32 A (layer 1), 1 = fp16-plane A (layers 2/3, lossless split).
template <int BN, int AMODE>
__global__ __launch_bounds__(512) void mfma_gemm(
    const float* __restrict__ Af, const f16* __restrict__ Ah16,
    const u16* __restrict__ Wfhi, const u16* __restrict__ Wflo,
    f16* __restrict__ Xh, int N, int K, int KP)
{
    constexpr int FC = BN / 16;
    constexpr int PLANE = BN * 32;            // u16 per plane per k-tile
    __shared__ u16 Wlds[2][2 * PLANE];        // [buf][hi | lo]
    const int tid = threadIdx.x;
    const int w = tid >> 6;                   // wave 0..7
    const int l = tid & 63;
    const int l15 = l & 15;
    const int g = l >> 4;
    const int koff = g * 8;
    const long base = (long)blockIdx.x * 128;
    const long arow = base + w * 16 + l15;
    const bool rowOK = (arow < N);
    const int bro = l * 8;                    // linear per-lane frag offset (u16)
    const int T = KP / 32;

    f32x4 acc[FC];
    #pragma unroll
    for (int j = 0; j < FC; ++j) acc[j] = (f32x4){0.f, 0.f, 0.f, 0.f};

    auto stageW = [&](int t, int buf) {
        if (BN == 128 || tid < PLANE / 8) {
            const u16* gph = Wfhi + (long)t * PLANE + tid * 8;
            const u16* gpl = Wflo + (long)t * PLANE + tid * 8;
            __builtin_amdgcn_global_load_lds(
                (const __attribute__((address_space(1))) void*)gph,
                (__attribute__((address_space(3))) void*)((char*)&Wlds[buf][0] + w * 1024), 16, 0, 0);
            __builtin_amdgcn_global_load_lds(
                (const __attribute__((address_space(1))) void*)gpl,
                (__attribute__((address_space(3))) void*)((char*)&Wlds[buf][PLANE] + w * 1024), 16, 0, 0);
        }
    };
    // raw A loads -- fp32 path
    auto loadRawF = [&](int t, f4u& ra, f4u& rb) {
        ra = (f4u){0.f, 0.f, 0.f, 0.f};
        rb = (f4u){0.f, 0.f, 0.f, 0.f};
        if (t < T) {
            int k0 = t * 32;
            int rem = K - (k0 + koff);
            if (rowOK && rem > 0) {
                const float* ap = &Af[arow * (long)K + k0 + koff];
                if (rem >= 8) {
                    ra = *(const f4u*)ap;
                    rb = *(const f4u*)(ap + 4);
                } else {
                    float f[8];
                    #pragma unroll
                    for (int j = 0; j < 8; ++j) f[j] = (j < rem) ? ap[j] : 0.f;
                    ra = (f4u){f[0], f[1], f[2], f[3]};
                    rb = (f4u){f[4], f[5], f[6], f[7]};
                }
            }
        }
    };
    auto convF = [&](const f4u& ra, const f4u& rb, bf16x8& ah, bf16x8& al) {
        float f[8] = {ra.x, ra.y, ra.z, ra.w, rb.x, rb.y, rb.z, rb.w};
        u16x8 hv, lv;
        #pragma unroll
        for (int j = 0; j < 8; ++j) {
            u16 h = bf16_rne(f[j]);
            hv[j] = h;
            lv[j] = bf16_rne(f[j] - bf16_f(h));
        }
        ah = __builtin_bit_cast(bf16x8, hv);
        al = __builtin_bit_cast(bf16x8, lv);
    };
    // raw A loads -- fp16-plane path (16B/lane)
    auto loadRawH = [&](int t, u16x8& q) {
        q = (u16x8)0;
        if (t < T && rowOK) {
            const int k0 = t * 32;
            q = *(const u16x8*)&Ah16[arow * (long)K + k0 + koff];
        }
    };
    auto convH = [&](const u16x8& q, bf16x8& ah, bf16x8& al) {
        f16x8 v = __builtin_bit_cast(f16x8, q);
        u16x8 hv, lv;
        #pragma unroll
        for (int j = 0; j < 8; ++j) {
            float f = (float)v[j];
            u16 h = bf16_rne(f);
            hv[j] = h;
            lv[j] = bf16_rne(f - bf16_f(h));
        }
        ah = __builtin_bit_cast(bf16x8, hv);
        al = __builtin_bit_cast(bf16x8, lv);
    };
    auto domfma = [&](const bf16x8& ah, const bf16x8& al, int buf) {
        #pragma unroll
        for (int fc = 0; fc < FC; ++fc) {
            bf16x8 bh = *(const bf16x8*)&Wlds[buf][fc * 512 + bro];
            bf16x8 bl = *(const bf16x8*)&Wlds[buf][PLANE + fc * 512 + bro];
            acc[fc] = __builtin_amdgcn_mfma_f32_16x16x32_bf16(ah, bh, acc[fc], 0, 0, 0);
            acc[fc] = __builtin_amdgcn_mfma_f32_16x16x32_bf16(al, bh, acc[fc], 0, 0, 0);
            acc[fc] = __builtin_amdgcn_mfma_f32_16x16x32_bf16(ah, bl, acc[fc], 0, 0, 0);
        }
    };

    // static slots (no dynamic indexing -> stay in registers)
    f4u r0a, r0b, r1a, r1b;
    u16x8 q0, q1;
    bf16x8 a0h, a0l, a1h, a1l;

    // prologue: W(0) staged; raw A(0), A(1) in flight; A(0) converted
    stageW(0, 0);
    if constexpr (AMODE == 0) {
        loadRawF(0, r0a, r0b);
        loadRawF(1, r1a, r1b);
        convF(r0a, r0b, a0h, a0l);
    } else {
        loadRawH(0, q0);
        loadRawH(1, q1);
        convH(q0, a0h, a0l);
    }
    __syncthreads();

    for (int t = 0; t < T; t += 2) {
        // ---- even tile: reads buf0
        if (t + 1 < T) stageW(t + 1, 1);
        if constexpr (AMODE == 0) loadRawF(t + 2, r0a, r0b);
        else                      loadRawH(t + 2, q0);
        domfma(a0h, a0l, 0);
        if constexpr (AMODE == 0) convF(r1a, r1b, a1h, a1l);
        else                      convH(q1, a1h, a1l);
        __syncthreads();
        // ---- odd tile: reads buf1
        if (t + 1 < T) {
            if (t + 2 < T) stageW(t + 2, 0);
            if constexpr (AMODE == 0) loadRawF(t + 3, r1a, r1b);
            else                      loadRawH(t + 3, q1);
            domfma(a1h, a1l, 1);
            if constexpr (AMODE == 0) convF(r0a, r0b, a0h, a0l);
            else                      convH(q0, a0h, a0l);
            __syncthreads();
        }
    }
    // ---- epilogue: fp16 plane. D col=lane&15, row=(lane>>4)*4+reg
    #pragma unroll
    for (int fc = 0; fc < FC; ++fc) {
        int col = fc * 16 + l15;
        #pragma unroll
        for (int reg = 0; reg < 4; ++reg) {
            long row = base + w * 16 + g * 4 + reg;
            if (row < N) Xh[row * BN + col] = (f16)acc[fc][reg];
        }
    }
}

// ---- aggregation from fp16 plane -> fp16 plane:
// h[i] = relu( sum_e xh[src_e]*nv_e + xh[i]*disq[i]^2 + bias ), fp32 accum.
template <int C>
__global__ __launch_bounds__(256) void agg_kernel(
    const f16* __restrict__ xh, const float* __restrict__ disq,
    const int* __restrict__ rp, const int2* __restrict__ esw,
    const float* __restrict__ bias, f16* __restrict__ hout, int N)
{
    int i = blockIdx.x * 4 + (threadIdx.x >> 6);
    if (i >= N) return;
    int lane = threadIdx.x & 63;
    int e0 = rp[i], e1 = rp[i + 1];
    constexpr int LPE = C / 8;            // lanes per edge (16 or 8)
    constexpr int EPW = 64 / LPE;         // edges per wave load (4 or 8)
    int sub = lane / LPE;
    int col = lane % LPE;                 // 8-half group within row
    const f16x8* x8 = (const f16x8*)xh;

    float a0[8], a1[8];
    #pragma unroll
    for (int j = 0; j < 8; ++j) { a0[j] = 0.f; a1[j] = 0.f; }

    int e = e0 + sub;
    for (; e + EPW < e1; e += 2 * EPW) {
        int2 p0 = esw[e];
        int2 p1 = esw[e + EPW];
        f16x8 v0 = x8[(long)p0.x * LPE + col];
        f16x8 v1 = x8[(long)p1.x * LPE + col];
        float w0 = __int_as_float(p0.y), w1 = __int_as_float(p1.y);
        #pragma unroll
        for (int j = 0; j < 8; ++j) {
            a0[j] += (float)v0[j] * w0;
            a1[j] += (float)v1[j] * w1;
        }
    }
    for (; e < e1; e += EPW) {
        int2 p0 = esw[e];
        f16x8 v0 = x8[(long)p0.x * LPE + col];
        float w0 = __int_as_float(p0.y);
        #pragma unroll
        for (int j = 0; j < 8; ++j) a0[j] += (float)v0[j] * w0;
    }
    #pragma unroll
    for (int j = 0; j < 8; ++j) a0[j] += a1[j];
    #pragma unroll
    for (int m = LPE; m < 64; m <<= 1) {
        #pragma unroll
        for (int j = 0; j < 8; ++j) a0[j] += __shfl_xor(a0[j], m, 64);
    }
    if (sub == 0) {
        float ds = disq[i];
        float ws = ds * ds;
        f16x8 v = x8[(long)i * LPE + col];
        const float* bp = bias + col * 8;
        float4 b0 = *(const float4*)bp;
        float4 b1 = *(const float4*)(bp + 4);
        float bb[8] = {b0.x, b0.y, b0.z, b0.w, b1.x, b1.y, b1.z, b1.w};
        f16x8 o;
        #pragma unroll
        for (int j = 0; j < 8; ++j)
            o[j] = (f16)fmaxf(a0[j] + (float)v[j] * ws + bb[j], 0.f);
        *(f16x8*)&hout[(long)i * C + col * 8] = o;
    }
}

// ---- global max pool (fp16 in): batch sorted -> running max, flush on change
__global__ __launch_bounds__(256) void pool_kernel(
    const f16* __restrict__ h, const int* __restrict__ batch,
    float* __restrict__ g, int N)
{
    int c = threadIdx.x & 63;
    int slot = threadIdx.x >> 6;
    int base = blockIdx.x * 512;
    int end = base + 512; if (end > N) end = N;
    int cur = -1; float m = 0.f;
    for (int n = base + slot; n < end; n += 4) {
        int b = batch[n];
        float v = (float)h[(long)n * 64 + c];
        if (b != cur) {
            if (cur >= 0) atomicMax((int*)&g[cur * 64 + c], __float_as_int(m));
            cur = b; m = v;
        } else {
            m = fmaxf(m, v);
        }
    }
    if (cur >= 0) atomicMax((int*)&g[cur * 64 + c], __float_as_int(m));
}

// ---- head: out[r] = relu(g[r]@Wh1+bh1) @ Wh2 + bh2
__global__ void head_kernel(const float* __restrict__ g, const float* __restrict__ Wh1,
                            const float* __restrict__ bh1, const float* __restrict__ Wh2,
                            const float* __restrict__ bh2, float* __restrict__ out, int G) {
    int r = threadIdx.x;
    if (r >= G) return;
    float hid[32];
    #pragma unroll
    for (int j = 0; j < 32; ++j) {
        float s = bh1[j];
        for (int k = 0; k < 64; ++k) s += g[r * 64 + k] * Wh1[k * 32 + j];
        hid[j] = fmaxf(s, 0.f);
    }
    float o = bh2[0];
    #pragma unroll
    for (int j = 0; j < 32; ++j) o += hid[j] * Wh2[j];
    out[r] = o;
}

extern "C" void kernel_launch(void* const* d_in, const int* in_sizes, int n_in,
                              void* d_out, int out_size, void* d_ws, size_t ws_size,
                              hipStream_t stream) {
    const float* x   = (const float*)d_in[0];
    const int*   ei  = (const int*)d_in[1];
    const int*   bat = (const int*)d_in[2];
    const float* W1  = (const float*)d_in[3];
    const float* b1  = (const float*)d_in[4];
    const float* W2  = (const float*)d_in[5];
    const float* b2  = (const float*)d_in[6];
    const float* W3  = (const float*)d_in[7];
    const float* b3  = (const float*)d_in[8];
    const float* Wh1 = (const float*)d_in[9];
    const float* bh1 = (const float*)d_in[10];
    const float* Wh2 = (const float*)d_in[11];
    const float* bh2 = (const float*)d_in[12];
    float* out = (float*)d_out;

    const int N = in_sizes[2];
    const int E = in_sizes[1] / 2;
    const int K1 = in_sizes[0] / N;          // 397
    const int G = out_size;                  // 64
    const int KP1 = ((K1 + 31) / 32) * 32;   // 416

    char* wsp = (char*)d_ws;
    size_t off = 0;
    auto alloc = [&](size_t bytes) -> void* {
        void* p = wsp + off;
        off = (off + bytes + 255) & ~(size_t)255;
        return p;
    };
    int*   cnt   = (int*)alloc((size_t)N * 4);
    float* disq  = (float*)alloc((size_t)N * 4);
    int*   rp    = (int*)alloc((size_t)(N + 1) * 4);
    int*   bsum  = (int*)alloc(256 * 4);
    int*   boff  = (int*)alloc(256 * 4);
    int2*  esw   = (int2*)alloc((size_t)E * 8);
    u16*   Wf1hi = (u16*)alloc((size_t)KP1 * 128 * 2);
    u16*   Wf1lo = (u16*)alloc((size_t)KP1 * 128 * 2);
    u16*   Wf2hi = (u16*)alloc((size_t)128 * 128 * 2);
    u16*   Wf2lo = (u16*)alloc((size_t)128 * 128 * 2);
    u16*   Wf3hi = (u16*)alloc((size_t)128 * 64 * 2);
    u16*   Wf3lo = (u16*)alloc((size_t)128 * 64 * 2);
    f16*   Xh    = (f16*)alloc((size_t)N * 128 * 2);     // GEMM out plane
    f16*   Hh    = (f16*)alloc((size_t)N * 128 * 2);     // agg out plane
    float* g     = (float*)alloc((size_t)G * 64 * 4);

    const int nchunks = (N + 1023) / 1024;

    (void)hipMemsetAsync(cnt, 0, (size_t)N * 4, stream);
    deg_count_kernel<<<(E + 255) / 256, 256, 0, stream>>>(ei, cnt, E);
    deg_fin_kernel<<<(N + 255) / 256, 256, 0, stream>>>(cnt, disq, N);
    scan_pass1<<<nchunks, 256, 0, stream>>>(cnt, bsum, N);
    scan_pass2<<<1, 256, 0, stream>>>(bsum, boff, nchunks, rp, N, E);
    scan_pass3<<<nchunks, 256, 0, stream>>>(cnt, boff, rp, N);
    (void)hipMemsetAsync(cnt, 0, (size_t)N * 4, stream);
    scatter_kernel<<<(E + 255) / 256, 256, 0, stream>>>(ei, disq, rp, cnt, esw, E);

    // weight conversions (tiny, read-lane-ordered fragments)
    cvtw_kernel<128><<<(KP1 * 128 + 255) / 256, 256, 0, stream>>>(W1, Wf1hi, Wf1lo, K1, KP1);
    cvtw_kernel<128><<<(128 * 128 + 255) / 256, 256, 0, stream>>>(W2, Wf2hi, Wf2lo, 128, 128);
    cvtw_kernel<64><<<(128 * 64 + 255) / 256, 256, 0, stream>>>(W3, Wf3hi, Wf3lo, 128, 128);

    int gblocks = (N + 127) / 128;
    int ablocks = (N + 3) / 4;
    // layer 1
    mfma_gemm<128, 0><<<gblocks, 512, 0, stream>>>(x, nullptr, Wf1hi, Wf1lo, Xh, N, K1, KP1);
    agg_kernel<128><<<ablocks, 256, 0, stream>>>(Xh, disq, rp, esw, b1, Hh, N);
    // layer 2
    mfma_gemm<128, 1><<<gblocks, 512, 0, stream>>>(nullptr, Hh, Wf2hi, Wf2lo, Xh, N, 128, 128);
    agg_kernel<128><<<ablocks, 256, 0, stream>>>(Xh, disq, rp, esw, b2, Hh, N);
    // layer 3 (output BN=64 plane reuses Xh; agg3 writes into Hh)
    mfma_gemm<64, 1><<<gblocks, 512, 0, stream>>>(nullptr, Hh, Wf3hi, Wf3lo, Xh, N, 128, 128);
    agg_kernel<64><<<ablocks, 256, 0, stream>>>(Xh, disq, rp, esw, b3, Hh, N);
    // pool + head
    (void)hipMemsetAsync(g, 0, (size_t)G * 64 * 4, stream);
    pool_kernel<<<(N + 511) / 512, 256, 0, stream>>>(Hh, bat, g, N);
    head_kernel<<<1, 64, 0, stream>>>(g, Wh1, bh1, Wh2, bh2, out, G);
}